// Round 1
// baseline (1768.401 us; speedup 1.0000x reference)
//
#include <hip/hip_runtime.h>
#include <math.h>

// H[r,t] = (1/128) * sum_l alpha_l * exp(j*pi*r*sin(theta_r_l)) * exp(-j*pi*t*sin(theta_t_l))
// NT = NR = 1024, L = 8192.
// Output: if out_size == 1024*1024        -> Re(H) only (complex cast to float32)
//         if out_size == 2*1024*1024      -> interleaved (re,im) = complex64 viewed as float32

#define N_T 1024
#define N_R 1024
#define L_RAYS 8192
#define TILE 64
#define KC 32

__global__ __launch_bounds__(256) void geo_channel_kernel(
    const float* __restrict__ alpha_re,
    const float* __restrict__ alpha_im,
    const float* __restrict__ theta_t,
    const float* __restrict__ theta_r,
    float* __restrict__ out,
    int interleaved)
{
    // per-chunk phasors: [ray][pos][re/im]
    __shared__ float sAr[KC][TILE][2];  // alpha-weighted receive phasor
    __shared__ float sAt[KC][TILE][2];  // transmit phasor (conjugated in MAC)

    const int tid = threadIdx.x;
    const int bid = blockIdx.x;
    const int r0 = (bid / (N_T / TILE)) * TILE;
    const int t0 = (bid % (N_T / TILE)) * TILE;

    const int tx = tid & 15;   // t sub-block
    const int ty = tid >> 4;   // r sub-block

    float accRe[4][4] = {{0.f}};
    float accIm[4][4] = {{0.f}};

    const float C  = 1.0f / 128.0f;           // sqrt(128) / (sqrt(2)*32*32)
    const float PI = 3.14159265358979323846f;

    for (int lc = 0; lc < L_RAYS; lc += KC) {
        __syncthreads();
        // Generate phasors for this ray chunk: 2*KC*TILE sincos, 256 threads.
        for (int idx = tid; idx < KC * TILE; idx += 256) {
            const int ll = idx >> 6;          // local ray (TILE=64)
            const int rr = idx & 63;          // local position
            const int l  = lc + ll;
            const float are = alpha_re[l] * C;
            const float aim = alpha_im[l] * C;
            // accurate sin: error here is amplified by pi*r (r up to 1023)
            const float srr = sinf(theta_r[l]);
            const float stt = sinf(theta_t[l]);
            // receive phasor * alpha
            {
                float x = (float)(r0 + rr) * srr;
                float f = x - 2.0f * rintf(0.5f * x);   // reduce mod 2 -> [-1,1]
                float s, c;
                __sincosf(PI * f, &s, &c);
                sAr[ll][rr][0] = are * c - aim * s;
                sAr[ll][rr][1] = are * s + aim * c;
            }
            // transmit phasor
            {
                float x = (float)(t0 + rr) * stt;
                float f = x - 2.0f * rintf(0.5f * x);
                float s, c;
                __sincosf(PI * f, &s, &c);
                sAt[ll][rr][0] = c;
                sAt[ll][rr][1] = s;
            }
        }
        __syncthreads();

        #pragma unroll 4
        for (int ll = 0; ll < KC; ++ll) {
            const float4 arv0 = *reinterpret_cast<const float4*>(&sAr[ll][ty * 4 + 0][0]);
            const float4 arv1 = *reinterpret_cast<const float4*>(&sAr[ll][ty * 4 + 2][0]);
            const float4 atv0 = *reinterpret_cast<const float4*>(&sAt[ll][tx * 4 + 0][0]);
            const float4 atv1 = *reinterpret_cast<const float4*>(&sAt[ll][tx * 4 + 2][0]);
            const float arre[4] = {arv0.x, arv0.z, arv1.x, arv1.z};
            const float arim[4] = {arv0.y, arv0.w, arv1.y, arv1.w};
            const float atre[4] = {atv0.x, atv0.z, atv1.x, atv1.z};
            const float atim[4] = {atv0.y, atv0.w, atv1.y, atv1.w};
            #pragma unroll
            for (int i = 0; i < 4; ++i) {
                #pragma unroll
                for (int j = 0; j < 4; ++j) {
                    // (a+jb)*(c-jd) = (ac+bd) + j(bc-ad)
                    accRe[i][j] = fmaf(arre[i], atre[j], fmaf(arim[i], atim[j], accRe[i][j]));
                    accIm[i][j] = fmaf(arim[i], atre[j], fmaf(-arre[i], atim[j], accIm[i][j]));
                }
            }
        }
    }

    // Write the 4x4 complex sub-tile.
    #pragma unroll
    for (int i = 0; i < 4; ++i) {
        const int r = r0 + ty * 4 + i;
        #pragma unroll
        for (int j = 0; j < 4; ++j) {
            const int t = t0 + tx * 4 + j;
            if (interleaved) {
                out[2 * (r * N_T + t) + 0] = accRe[i][j];
                out[2 * (r * N_T + t) + 1] = accIm[i][j];
            } else {
                out[r * N_T + t] = accRe[i][j];
            }
        }
    }
}

extern "C" void kernel_launch(void* const* d_in, const int* in_sizes, int n_in,
                              void* d_out, int out_size, void* d_ws, size_t ws_size,
                              hipStream_t stream) {
    const float* alpha_re = (const float*)d_in[0];
    const float* alpha_im = (const float*)d_in[1];
    const float* theta_t  = (const float*)d_in[2];
    const float* theta_r  = (const float*)d_in[3];
    float* out = (float*)d_out;

    const int interleaved = (out_size >= 2 * N_R * N_T) ? 1 : 0;

    const int nblocks = (N_R / TILE) * (N_T / TILE);   // 256
    geo_channel_kernel<<<nblocks, 256, 0, stream>>>(
        alpha_re, alpha_im, theta_t, theta_r, out, interleaved);
}

// Round 2
// 81.936 us; speedup vs baseline: 21.5828x; 21.5828x over previous
//
#include <hip/hip_runtime.h>
#include <math.h>
#include <stdint.h>

// H[r,t] = (1/128) * sum_l alpha_l * exp(j*pi*r*sin(theta_r_l)) * exp(-j*pi*t*sin(theta_t_l))
// Output observed: out_size == 1024*1024 -> Re(H) only.
// Re(H)[r,t] = sum_l [aRe*cRe + aIm*cIm'] -> one real GEMM with K = 2L:
//   A[r][l]      = C*(are*cos(phi_r) - aim*sin(phi_r)),  phi_r = pi*r*sin(theta_r_l)
//   A[r][L+l]    = C*(are*sin(phi_r) + aim*cos(phi_r))
//   B[t][l]      = cos(psi_t),  psi_t = pi*t*sin(theta_t_l)
//   B[t][L+l]    = sin(psi_t)
//   Re(H) = A * B^T   (both row-major [1024][16384], bf16)

#define N_T 1024
#define N_R 1024
#define L_RAYS 8192
#define KDIM (2 * L_RAYS)  // 16384

typedef __attribute__((ext_vector_type(8))) short bf16x8;
typedef __attribute__((ext_vector_type(4))) float f32x4;

static __device__ __forceinline__ unsigned short f2bf(float x) {
    unsigned u = __builtin_bit_cast(unsigned, x);
    unsigned r = (u + 0x7FFFu + ((u >> 16) & 1u)) >> 16;
    return (unsigned short)r;
}

// ---------------------------------------------------------------- precompute
__global__ __launch_bounds__(256) void precomp_kernel(
    const float* __restrict__ alpha_re, const float* __restrict__ alpha_im,
    const float* __restrict__ theta_t, const float* __restrict__ theta_r,
    float* __restrict__ pre /* [4][L]: sr, st, ar*C, ai*C */)
{
    const int l = blockIdx.x * 256 + threadIdx.x;
    if (l < L_RAYS) {
        const float C = 1.0f / 128.0f;
        pre[0 * L_RAYS + l] = sinf(theta_r[l]);
        pre[1 * L_RAYS + l] = sinf(theta_t[l]);
        pre[2 * L_RAYS + l] = alpha_re[l] * C;
        pre[3 * L_RAYS + l] = alpha_im[l] * C;
    }
}

// ---------------------------------------------------------------- phasor gen
__global__ __launch_bounds__(256) void gen_kernel(
    const float* __restrict__ pre,
    unsigned short* __restrict__ Amat,  // [N_R][KDIM] bf16
    unsigned short* __restrict__ Bmat)  // [N_T][KDIM] bf16
{
    const unsigned gid = blockIdx.x * 256 + threadIdx.x;
    const unsigned mat = gid >> 20;            // 0 = A, 1 = B
    const unsigned rem = gid & 0xFFFFFu;
    const unsigned pos = rem >> 10;            // 0..1023
    const unsigned lc  = (rem & 1023u) * 8u;   // ray chunk base
    const float PI = 3.14159265358979323846f;

    bf16x8 vre, vim;
    if (mat == 0) {
        #pragma unroll
        for (int j = 0; j < 8; ++j) {
            const int l = lc + j;
            const float s  = pre[l];
            const float ar = pre[2 * L_RAYS + l];
            const float ai = pre[3 * L_RAYS + l];
            float x = (float)pos * s;
            float f = x - 2.0f * rintf(0.5f * x);
            float sn, cs;
            __sincosf(PI * f, &sn, &cs);
            vre[j] = (short)f2bf(ar * cs - ai * sn);
            vim[j] = (short)f2bf(ar * sn + ai * cs);
        }
        *reinterpret_cast<bf16x8*>(&Amat[(size_t)pos * KDIM + lc]) = vre;
        *reinterpret_cast<bf16x8*>(&Amat[(size_t)pos * KDIM + L_RAYS + lc]) = vim;
    } else {
        #pragma unroll
        for (int j = 0; j < 8; ++j) {
            const int l = lc + j;
            const float s = pre[L_RAYS + l];
            float x = (float)pos * s;
            float f = x - 2.0f * rintf(0.5f * x);
            float sn, cs;
            __sincosf(PI * f, &sn, &cs);
            vre[j] = (short)f2bf(cs);
            vim[j] = (short)f2bf(sn);
        }
        *reinterpret_cast<bf16x8*>(&Bmat[(size_t)pos * KDIM + lc]) = vre;
        *reinterpret_cast<bf16x8*>(&Bmat[(size_t)pos * KDIM + L_RAYS + lc]) = vim;
    }
}

// ---------------------------------------------------------------- bf16 GEMM
// C = A * B^T, A[NR][K], B[NT][K] row-major bf16, split-K partials in fp32.
#define BM 128
#define BN 128
#define BK 32

__global__ __launch_bounds__(256) void gemm_kernel(
    const unsigned short* __restrict__ Amat,
    const unsigned short* __restrict__ Bmat,
    float* __restrict__ Pout,   // [splitk][N_R][N_T] (== out when splitk==1)
    int ksteps_per)
{
    __shared__ unsigned short As[2][BM * BK];
    __shared__ unsigned short Bs[2][BN * BK];

    const int tid  = threadIdx.x;
    const int wave = tid >> 6;
    const int lane = tid & 63;

    const int bid  = blockIdx.x;
    const int tile = bid & 63;
    const int sk   = bid >> 6;
    const int r0 = (tile >> 3) * BM;
    const int c0 = (tile & 7) * BN;
    const int k_begin = sk * (ksteps_per * BK);

    // stage one K-step tile (A and B) into LDS buffer `buf`
    auto stage = [&](int buf, int kt) {
        const int k0 = k_begin + kt * BK;
        #pragma unroll
        for (int i = 0; i < 2; ++i) {
            const int rowbase = (i * 4 + wave) * 16;
            const int row = rowbase + (lane >> 2);
            {
                const unsigned short* g = Amat + (size_t)(r0 + row) * KDIM + k0 + (lane & 3) * 8;
                unsigned short* lp = &As[buf][rowbase * BK];
                __builtin_amdgcn_global_load_lds(
                    (const __attribute__((address_space(1))) unsigned int*)g,
                    (__attribute__((address_space(3))) unsigned int*)lp, 16, 0, 0);
            }
            {
                const unsigned short* g = Bmat + (size_t)(c0 + row) * KDIM + k0 + (lane & 3) * 8;
                unsigned short* lp = &Bs[buf][rowbase * BK];
                __builtin_amdgcn_global_load_lds(
                    (const __attribute__((address_space(1))) unsigned int*)g,
                    (__attribute__((address_space(3))) unsigned int*)lp, 16, 0, 0);
            }
        }
    };

    f32x4 acc[4][4];
    #pragma unroll
    for (int m = 0; m < 4; ++m)
        #pragma unroll
        for (int n = 0; n < 4; ++n)
            acc[m][n] = (f32x4){0.f, 0.f, 0.f, 0.f};

    const int wr = wave >> 1, wc = wave & 1;
    const int arow = wr * 64 + (lane & 15);
    const int brow = wc * 64 + (lane & 15);
    const int koff = (lane >> 4) * 8;

    stage(0, 0);
    __syncthreads();
    int cur = 0;
    for (int kt = 0; kt < ksteps_per; ++kt) {
        if (kt + 1 < ksteps_per) stage(cur ^ 1, kt + 1);
        bf16x8 a[4], b[4];
        #pragma unroll
        for (int m = 0; m < 4; ++m)
            a[m] = *reinterpret_cast<const bf16x8*>(&As[cur][(arow + m * 16) * BK + koff]);
        #pragma unroll
        for (int n = 0; n < 4; ++n)
            b[n] = *reinterpret_cast<const bf16x8*>(&Bs[cur][(brow + n * 16) * BK + koff]);
        #pragma unroll
        for (int m = 0; m < 4; ++m)
            #pragma unroll
            for (int n = 0; n < 4; ++n)
                acc[m][n] = __builtin_amdgcn_mfma_f32_16x16x32_bf16(a[m], b[n], acc[m][n], 0, 0, 0);
        __syncthreads();
        cur ^= 1;
    }

    // C/D layout (m89/m91): col = lane&15, row = (lane>>4)*4 + reg
    float* P = Pout + (size_t)sk * (N_R * N_T);
    const int crow0 = r0 + wr * 64 + (lane >> 4) * 4;
    const int ccol0 = c0 + wc * 64 + (lane & 15);
    #pragma unroll
    for (int m = 0; m < 4; ++m)
        #pragma unroll
        for (int n = 0; n < 4; ++n)
            #pragma unroll
            for (int j = 0; j < 4; ++j)
                P[(size_t)(crow0 + m * 16 + j) * N_T + ccol0 + n * 16] = acc[m][n][j];
}

// ---------------------------------------------------------------- reduce
__global__ __launch_bounds__(256) void reduce_kernel(
    const f32x4* __restrict__ P, f32x4* __restrict__ out, int splitk)
{
    const int i = blockIdx.x * 256 + threadIdx.x;  // over N_R*N_T/4
    const int n4 = (N_R * N_T) / 4;
    f32x4 s = P[i];
    for (int sk = 1; sk < splitk; ++sk) s += P[(size_t)sk * n4 + i];
    out[i] = s;
}

// ---------------------------------------------------------------- fp32 fallback
#define TILE 64
#define KC 32
__global__ __launch_bounds__(256) void geo_channel_fallback(
    const float* __restrict__ alpha_re, const float* __restrict__ alpha_im,
    const float* __restrict__ theta_t, const float* __restrict__ theta_r,
    float* __restrict__ out, int interleaved)
{
    __shared__ float sAr[KC][TILE][2];
    __shared__ float sAt[KC][TILE][2];
    const int tid = threadIdx.x;
    const int bid = blockIdx.x;
    const int r0 = (bid / (N_T / TILE)) * TILE;
    const int t0 = (bid % (N_T / TILE)) * TILE;
    const int tx = tid & 15;
    const int ty = tid >> 4;
    float accRe[4][4] = {{0.f}};
    float accIm[4][4] = {{0.f}};
    const float C = 1.0f / 128.0f;
    const float PI = 3.14159265358979323846f;
    for (int lc = 0; lc < L_RAYS; lc += KC) {
        __syncthreads();
        for (int idx = tid; idx < KC * TILE; idx += 256) {
            const int ll = idx >> 6;
            const int rr = idx & 63;
            const int l = lc + ll;
            const float are = alpha_re[l] * C;
            const float aim = alpha_im[l] * C;
            const float srr = sinf(theta_r[l]);
            const float stt = sinf(theta_t[l]);
            {
                float x = (float)(r0 + rr) * srr;
                float f = x - 2.0f * rintf(0.5f * x);
                float s, c;
                __sincosf(PI * f, &s, &c);
                sAr[ll][rr][0] = are * c - aim * s;
                sAr[ll][rr][1] = are * s + aim * c;
            }
            {
                float x = (float)(t0 + rr) * stt;
                float f = x - 2.0f * rintf(0.5f * x);
                float s, c;
                __sincosf(PI * f, &s, &c);
                sAt[ll][rr][0] = c;
                sAt[ll][rr][1] = s;
            }
        }
        __syncthreads();
        #pragma unroll 4
        for (int ll = 0; ll < KC; ++ll) {
            const float4 arv0 = *reinterpret_cast<const float4*>(&sAr[ll][ty * 4 + 0][0]);
            const float4 arv1 = *reinterpret_cast<const float4*>(&sAr[ll][ty * 4 + 2][0]);
            const float4 atv0 = *reinterpret_cast<const float4*>(&sAt[ll][tx * 4 + 0][0]);
            const float4 atv1 = *reinterpret_cast<const float4*>(&sAt[ll][tx * 4 + 2][0]);
            const float arre[4] = {arv0.x, arv0.z, arv1.x, arv1.z};
            const float arim[4] = {arv0.y, arv0.w, arv1.y, arv1.w};
            const float atre[4] = {atv0.x, atv0.z, atv1.x, atv1.z};
            const float atim[4] = {atv0.y, atv0.w, atv1.y, atv1.w};
            #pragma unroll
            for (int i = 0; i < 4; ++i)
                #pragma unroll
                for (int j = 0; j < 4; ++j) {
                    accRe[i][j] = fmaf(arre[i], atre[j], fmaf(arim[i], atim[j], accRe[i][j]));
                    accIm[i][j] = fmaf(arim[i], atre[j], fmaf(-arre[i], atim[j], accIm[i][j]));
                }
        }
    }
    #pragma unroll
    for (int i = 0; i < 4; ++i) {
        const int r = r0 + ty * 4 + i;
        #pragma unroll
        for (int j = 0; j < 4; ++j) {
            const int t = t0 + tx * 4 + j;
            if (interleaved) {
                out[2 * (r * N_T + t) + 0] = accRe[i][j];
                out[2 * (r * N_T + t) + 1] = accIm[i][j];
            } else {
                out[r * N_T + t] = accRe[i][j];
            }
        }
    }
}

// ---------------------------------------------------------------- launch
extern "C" void kernel_launch(void* const* d_in, const int* in_sizes, int n_in,
                              void* d_out, int out_size, void* d_ws, size_t ws_size,
                              hipStream_t stream) {
    const float* alpha_re = (const float*)d_in[0];
    const float* alpha_im = (const float*)d_in[1];
    const float* theta_t  = (const float*)d_in[2];
    const float* theta_r  = (const float*)d_in[3];
    float* out = (float*)d_out;

    const int interleaved = (out_size >= 2 * N_R * N_T) ? 1 : 0;

    // ws layout: A (32MB) | B (32MB) | pre (128KB) | partials (splitk*4MB)
    const size_t offA   = 0;
    const size_t offB   = (size_t)N_R * KDIM * 2;                    // 32 MB
    const size_t offPre = offB + (size_t)N_T * KDIM * 2;             // 64 MB
    const size_t offP   = offPre + (size_t)4 * L_RAYS * 4;           // +128 KB

    int splitk = 0;
    for (int s = 8; s >= 1; s >>= 1) {
        const size_t need = offP + (s > 1 ? (size_t)s * N_R * N_T * 4 : 0);
        if (ws_size >= need) { splitk = s; break; }
    }

    if (interleaved || splitk == 0) {
        const int nblocks = (N_R / TILE) * (N_T / TILE);
        geo_channel_fallback<<<nblocks, 256, 0, stream>>>(
            alpha_re, alpha_im, theta_t, theta_r, out, interleaved);
        return;
    }

    char* ws = (char*)d_ws;
    unsigned short* Amat = (unsigned short*)(ws + offA);
    unsigned short* Bmat = (unsigned short*)(ws + offB);
    float* pre = (float*)(ws + offPre);
    float* P   = (splitk == 1) ? out : (float*)(ws + offP);

    precomp_kernel<<<(L_RAYS + 255) / 256, 256, 0, stream>>>(
        alpha_re, alpha_im, theta_t, theta_r, pre);
    gen_kernel<<<(2 * 1024 * 1024) / 256, 256, 0, stream>>>(pre, Amat, Bmat);

    const int ksteps_per = KDIM / (splitk * BK);
    gemm_kernel<<<64 * splitk, 256, 0, stream>>>(Amat, Bmat, P, ksteps_per);

    if (splitk > 1)
        reduce_kernel<<<(N_R * N_T / 4) / 256, 256, 0, stream>>>(
            (const f32x4*)P, (f32x4*)out, splitk);
}